// Round 1
// 182.792 us; speedup vs baseline: 1.0085x; 1.0085x over previous
//
#include <hip/hip_runtime.h>
#include <hip/hip_bf16.h>
#include <stdint.h>

#define N_MODELS 16
#define IN_F 1024
#define OUT_F 1024
#define N_TOK 8192
#define MAX_MT 80          // max m-tiles: 64 full + up to 15 fragmentation

typedef unsigned short u16;
using us4   = __attribute__((ext_vector_type(4))) unsigned short;
using s16x8 = __attribute__((ext_vector_type(8))) short;
using f32x4 = __attribute__((ext_vector_type(4))) float;

__device__ __forceinline__ u16 f2bf(float f) {
    union { float f; uint32_t u; } v;
    v.f = f;
    uint32_t u = v.u;
    u += 0x7fffu + ((u >> 16) & 1u);   // RNE
    return (u16)(u >> 16);
}

__device__ __forceinline__ void gload16(const u16* g, u16* l) {
    // async global->LDS DMA, 16 B/lane; LDS dest = wave-uniform base + lane*16
    __builtin_amdgcn_global_load_lds(
        (const __attribute__((address_space(1))) void*)g,
        (__attribute__((address_space(3))) void*)l, 16, 0, 0);
}

// ---------------- kernel 1: fused w-convert (blocks 1..2048) + setup (block 0) ----------------
// setup: hist + scan + deterministic rank scatter (1 block, runs concurrently with w-blocks;
//        w-conversion has no dependency on it)
// w-path: fp32 [k][n] -> bf16 frag-major, NO LDS:
//   lane-contiguous n => 8x scalar loads are 256 B/wave contiguous; s16x8 store is 1 KB/wave.
// wT layout (u16): (e*8 + nt)*131072 + ko_g*1024 + n*8 + j    (ko_g: global k-octet 0..127)
#define ROW 17   // LDS row stride (ints) for [256][16] tables -> conflict-free
#define WBLOCKS 2048   // (e, nt, 64-k group)

__global__ __launch_bounds__(256)
void wprep_setup_kernel(const float* __restrict__ w,
                        const int* __restrict__ idxs,
                        int* __restrict__ perm,
                        int* __restrict__ offs,       // [17]
                        int* __restrict__ tile_off,   // [17]
                        u16* __restrict__ wT)
{
    __shared__ int cnt[256 * ROW];
    __shared__ int offsS[N_MODELS + 1];
    int t  = threadIdx.x;
    int bx = blockIdx.x;

    if (bx == 0) {
        // ---- setup: histogram + scan + rank scatter (unchanged logic) ----
#pragma unroll
        for (int e = 0; e < N_MODELS; ++e) cnt[t * ROW + e] = 0;
        __syncthreads();

        int base = t * 32;
#pragma unroll
        for (int i = 0; i < 32; ++i) cnt[t * ROW + idxs[base + i]] += 1;
        __syncthreads();

#pragma unroll
        for (int s = 1; s < 256; s <<= 1) {
            int v[N_MODELS];
#pragma unroll
            for (int e = 0; e < N_MODELS; ++e)
                v[e] = (t >= s) ? cnt[(t - s) * ROW + e] : 0;
            __syncthreads();
#pragma unroll
            for (int e = 0; e < N_MODELS; ++e)
                cnt[t * ROW + e] += v[e];
            __syncthreads();
        }

        if (t == 0) {
            int o = 0, to = 0;
            for (int e = 0; e < N_MODELS; ++e) {
                int c = cnt[255 * ROW + e];
                offsS[e] = o;
                offs[e] = o; tile_off[e] = to;
                to += (c + 127) >> 7;
                o  += c;
            }
            offsS[N_MODELS] = o;
            offs[N_MODELS] = o; tile_off[N_MODELS] = to;
        }
        __syncthreads();

        int cur[N_MODELS];
#pragma unroll
        for (int e = 0; e < N_MODELS; ++e)
            cur[e] = offsS[e] + ((t > 0) ? cnt[(t - 1) * ROW + e] : 0);
        __syncthreads();
#pragma unroll
        for (int e = 0; e < N_MODELS; ++e) cnt[t * ROW + e] = cur[e];

#pragma unroll
        for (int i = 0; i < 32; ++i) {
            int tok = base + i;
            int e = idxs[tok];
            perm[cnt[t * ROW + e]++] = tok;
        }
        return;
    }

    // ---- w-path: direct strided-coalesced transform, no LDS / no barriers ----
    int wb = bx - 1;             // 0..2047
    int e  = wb >> 7;
    int nt = (wb >> 4) & 7;
    int kg = wb & 15;            // 64-k group
    int n    = t & 127;          // lane-contiguous output column
    int half = t >> 7;

    const float* wp = w  + (size_t)e * (IN_F * OUT_F) + (size_t)nt * 128 + n;
    u16*         ob = wT + ((size_t)(e * 8 + nt)) * 131072 + (size_t)n * 8;

#pragma unroll
    for (int i = 0; i < 4; ++i) {
        int kog = kg * 8 + half + i * 2;   // global k-octet
        float r[8];
#pragma unroll
        for (int j = 0; j < 8; ++j)
            r[j] = wp[(size_t)(kog * 8 + j) * OUT_F];   // 256 B/wave contiguous per instr
        union { __hip_bfloat162 h; uint32_t u; } c0, c1, c2, c3;
        c0.h = __float22bfloat162_rn(make_float2(r[0], r[1]));
        c1.h = __float22bfloat162_rn(make_float2(r[2], r[3]));
        c2.h = __float22bfloat162_rn(make_float2(r[4], r[5]));
        c3.h = __float22bfloat162_rn(make_float2(r[6], r[7]));
        union { s16x8 v; uint32_t u[4]; } outv;
        outv.u[0] = c0.u; outv.u[1] = c1.u; outv.u[2] = c2.u; outv.u[3] = c3.u;
        *(s16x8*)(ob + (size_t)kog * 1024) = outv.v;    // 1 KB/wave contiguous
    }
}

// ---------------- kernel 2: x-gather fp32 -> bf16 frag-major, NO LDS ----------------
// xg layout (u16): mt*131072 + kb*4096 + q*1024 + r*8 + j   (k = kb*32 + q*8 + j)
// per-wave: float4 gather forms 128 B segments per token row; us4 stores form
// 4 x 128 B contiguous segments per wave -> cache-line granular both ways.
#define XBLOCKS (MAX_MT * 8)    // (mt, 128-k group)

__global__ __launch_bounds__(256)
void xprep_kernel(const float* __restrict__ x,
                  const int* __restrict__ perm, const int* __restrict__ offs,
                  const int* __restrict__ tile_off,
                  u16* __restrict__ xg)
{
    int t  = threadIdx.x;
    int bx = blockIdx.x;
    int mt = bx >> 3;
    int kg = bx & 7;             // 128-k group
    int total = tile_off[N_MODELS];
    if (mt >= total) return;
    int e = 0;
    while (tile_off[e + 1] <= mt) ++e;
    int s0   = offs[e] + (mt - tile_off[e]) * 128;
    int sEnd = offs[e + 1];

    int r0   = t >> 3;           // 0..31
    int apos = t & 7;
    int q    = apos >> 1;
    int j0   = (apos & 1) * 4;

    int toks[4];
#pragma unroll
    for (int i = 0; i < 4; ++i) {
        int r = r0 + i * 32;
        toks[i] = (s0 + r < sEnd) ? perm[s0 + r] : -1;
    }

    u16* outx = xg + (size_t)mt * 131072;
#pragma unroll
    for (int kb4 = 0; kb4 < 4; ++kb4) {
        int kb = kg * 4 + kb4;
        int k  = kb * 32 + apos * 4;
#pragma unroll
        for (int i = 0; i < 4; ++i) {
            int r = r0 + i * 32;
            float4 v;
            if (toks[i] >= 0) v = *(const float4*)(x + (size_t)toks[i] * IN_F + k);
            else              v = make_float4(0.f, 0.f, 0.f, 0.f);
            us4 pk; pk.x = f2bf(v.x); pk.y = f2bf(v.y); pk.z = f2bf(v.z); pk.w = f2bf(v.w);
            *(us4*)(outx + (size_t)kb * 4096 + (size_t)q * 1024 + r * 8 + j0) = pk;
        }
    }
}

// ---------------- kernel 3: grouped GEMM + bias + relu (m97 structure, pure DMA) ----------------
__global__ __launch_bounds__(256)
void gemm_kernel(const u16* __restrict__ xg, const u16* __restrict__ wT,
                 const float* __restrict__ bias,
                 const int* __restrict__ perm, const int* __restrict__ offs,
                 const int* __restrict__ tile_off,
                 float* __restrict__ out)
{
    __shared__ u16 As[4096];
    __shared__ u16 Bs[4096];
    __shared__ int   permS[128];
    __shared__ float biasS[128];
    __shared__ int   toS[N_MODELS + 1];

    int t  = threadIdx.x;
    int bt = blockIdx.y;            // flat m-tile id
    int nt = blockIdx.x;            // n-tile id

    if (t <= N_MODELS) toS[t] = tile_off[t];
    __syncthreads();
    if (bt >= toS[N_MODELS]) return;   // uniform

    int e = 0;
    while (toS[e + 1] <= bt) ++e;
    int s0   = offs[e] + (bt - toS[e]) * 128;
    int sEnd = offs[e + 1];
    int mValid = sEnd - s0; if (mValid > 128) mValid = 128;

    if (t < 128) {
        permS[t] = (s0 + t < sEnd) ? perm[s0 + t] : 0;
        biasS[t] = bias[(size_t)e * OUT_F + nt * 128 + t];
    }

    const u16* atile = xg + (size_t)bt * 32 * 4096;
    const u16* btile = wT + ((size_t)(e * 8 + nt)) * 131072;

    int lane = t & 63;
    int wv   = t >> 6;
    int wm   = (wv >> 1) * 64;
    int wn   = (wv & 1) * 64;
    int m    = lane & 15;
    int q    = lane >> 4;

    f32x4 acc[4][4];
#pragma unroll
    for (int i = 0; i < 4; ++i)
#pragma unroll
        for (int j = 0; j < 4; ++j)
            acc[i][j] = (f32x4){0.f, 0.f, 0.f, 0.f};

    int c = wv * 2;   // this wave's 1 KB chunk base (8 chunks per 8 KB tile)

    for (int kb = 0; kb < 32; ++kb) {
        const u16* ga = atile + kb * 4096;
        const u16* gb = btile + kb * 4096;
        gload16(ga + (c    ) * 512 + lane * 8, &As[(c    ) * 512]);
        gload16(ga + (c + 1) * 512 + lane * 8, &As[(c + 1) * 512]);
        gload16(gb + (c    ) * 512 + lane * 8, &Bs[(c    ) * 512]);
        gload16(gb + (c + 1) * 512 + lane * 8, &Bs[(c + 1) * 512]);
        __syncthreads();

        s16x8 af[4], bf[4];
#pragma unroll
        for (int mt2 = 0; mt2 < 4; ++mt2)
            af[mt2] = *(const s16x8*)(&As[q * 1024 + (wm + mt2 * 16 + m) * 8]);
#pragma unroll
        for (int nt2 = 0; nt2 < 4; ++nt2)
            bf[nt2] = *(const s16x8*)(&Bs[q * 1024 + (wn + nt2 * 16 + m) * 8]);
#pragma unroll
        for (int mt2 = 0; mt2 < 4; ++mt2)
#pragma unroll
            for (int nt2 = 0; nt2 < 4; ++nt2)
                acc[mt2][nt2] = __builtin_amdgcn_mfma_f32_16x16x32_bf16(
                    af[mt2], bf[nt2], acc[mt2][nt2], 0, 0, 0);
        __syncthreads();
    }

    // epilogue: bias + relu, scatter rows by perm
#pragma unroll
    for (int mt2 = 0; mt2 < 4; ++mt2) {
        int rbase = wm + mt2 * 16 + q * 4;
#pragma unroll
        for (int i = 0; i < 4; ++i) {
            int r = rbase + i;
            if (r < mValid) {
                int tok = permS[r];
                float* orow = out + (size_t)tok * OUT_F + nt * 128;
#pragma unroll
                for (int nt2 = 0; nt2 < 4; ++nt2) {
                    int col = wn + nt2 * 16 + m;
                    float v = acc[mt2][nt2][i] + biasS[col];
                    orow[col] = v > 0.f ? v : 0.f;
                }
            }
        }
    }
}

extern "C" void kernel_launch(void* const* d_in, const int* in_sizes, int n_in,
                              void* d_out, int out_size, void* d_ws, size_t ws_size,
                              hipStream_t stream) {
    const float* x    = (const float*)d_in[0];
    const int*   idxs = (const int*)d_in[1];
    const float* w    = (const float*)d_in[2];
    const float* b    = (const float*)d_in[3];
    float* out = (float*)d_out;

    // ws layout: wT u16[16M] (32 MB) | xg u16[80*32*4096] (20 MB) | perm | offs | tile_off
    u16* wT = (u16*)d_ws;
    u16* xg = wT + (size_t)N_MODELS * IN_F * OUT_F;
    int* perm     = (int*)(xg + (size_t)MAX_MT * 32 * 4096);
    int* offs     = perm + N_TOK;
    int* tile_off = offs + (N_MODELS + 1);

    // block 0 = setup (independent of w-blocks; x-gather launches after, so the
    // dependency is satisfied by kernel-boundary ordering regardless of dispatch order)
    wprep_setup_kernel<<<WBLOCKS + 1, 256, 0, stream>>>(w, idxs, perm, offs, tile_off, wT);
    xprep_kernel<<<XBLOCKS, 256, 0, stream>>>(x, perm, offs, tile_off, xg);
    gemm_kernel<<<dim3(8, MAX_MT), 256, 0, stream>>>(xg, wT, b, perm, offs, tile_off, out);
}

// Round 2
// 180.624 us; speedup vs baseline: 1.0206x; 1.0120x over previous
//
#include <hip/hip_runtime.h>
#include <hip/hip_bf16.h>
#include <stdint.h>

#define N_MODELS 16
#define IN_F 1024
#define OUT_F 1024
#define N_TOK 8192
#define MAX_MT 80          // max m-tiles: 64 full + up to 15 fragmentation

typedef unsigned short u16;
using us4   = __attribute__((ext_vector_type(4))) unsigned short;
using s16x8 = __attribute__((ext_vector_type(8))) short;
using f32x4 = __attribute__((ext_vector_type(4))) float;

__device__ __forceinline__ u16 f2bf(float f) {
    union { float f; uint32_t u; } v;
    v.f = f;
    uint32_t u = v.u;
    u += 0x7fffu + ((u >> 16) & 1u);   // RNE
    return (u16)(u >> 16);
}

__device__ __forceinline__ void gload16(const u16* g, u16* l) {
    // async global->LDS DMA, 16 B/lane; LDS dest = wave-uniform base + lane*16
    __builtin_amdgcn_global_load_lds(
        (const __attribute__((address_space(1))) void*)g,
        (__attribute__((address_space(3))) void*)l, 16, 0, 0);
}

// ---------------- kernel 1: fused w-convert (blocks 1..2048) + setup (block 0) ----------------
// setup: hist + scan + deterministic rank scatter (1 block, runs concurrently with w-blocks;
//        w-conversion has no dependency on it)
// w-path: fp32 [k][n] -> bf16 frag-major, NO LDS:
//   lane-contiguous n => 8x scalar loads are 256 B/wave contiguous; s16x8 store is 1 KB/wave.
// wT layout (u16): (e*8 + nt)*131072 + ko_g*1024 + n*8 + j    (ko_g: global k-octet 0..127)
#define ROW 17   // LDS row stride (ints) for [256][16] tables -> conflict-free
#define WBLOCKS 2048   // (e, nt, 64-k group)

__global__ __launch_bounds__(256)
void wprep_setup_kernel(const float* __restrict__ w,
                        const int* __restrict__ idxs,
                        int* __restrict__ perm,
                        int* __restrict__ offs,       // [17]
                        int* __restrict__ tile_off,   // [17]
                        u16* __restrict__ wT)
{
    __shared__ int cnt[256 * ROW];
    __shared__ int offsS[N_MODELS + 1];
    int t  = threadIdx.x;
    int bx = blockIdx.x;

    if (bx == 0) {
        // ---- setup: histogram + scan + rank scatter (unchanged logic) ----
#pragma unroll
        for (int e = 0; e < N_MODELS; ++e) cnt[t * ROW + e] = 0;
        __syncthreads();

        int base = t * 32;
#pragma unroll
        for (int i = 0; i < 32; ++i) cnt[t * ROW + idxs[base + i]] += 1;
        __syncthreads();

#pragma unroll
        for (int s = 1; s < 256; s <<= 1) {
            int v[N_MODELS];
#pragma unroll
            for (int e = 0; e < N_MODELS; ++e)
                v[e] = (t >= s) ? cnt[(t - s) * ROW + e] : 0;
            __syncthreads();
#pragma unroll
            for (int e = 0; e < N_MODELS; ++e)
                cnt[t * ROW + e] += v[e];
            __syncthreads();
        }

        if (t == 0) {
            int o = 0, to = 0;
            for (int e = 0; e < N_MODELS; ++e) {
                int c = cnt[255 * ROW + e];
                offsS[e] = o;
                offs[e] = o; tile_off[e] = to;
                to += (c + 127) >> 7;
                o  += c;
            }
            offsS[N_MODELS] = o;
            offs[N_MODELS] = o; tile_off[N_MODELS] = to;
        }
        __syncthreads();

        int cur[N_MODELS];
#pragma unroll
        for (int e = 0; e < N_MODELS; ++e)
            cur[e] = offsS[e] + ((t > 0) ? cnt[(t - 1) * ROW + e] : 0);
        __syncthreads();
#pragma unroll
        for (int e = 0; e < N_MODELS; ++e) cnt[t * ROW + e] = cur[e];

#pragma unroll
        for (int i = 0; i < 32; ++i) {
            int tok = base + i;
            int e = idxs[tok];
            perm[cnt[t * ROW + e]++] = tok;
        }
        return;
    }

    // ---- w-path: direct strided-coalesced transform, no LDS / no barriers ----
    int wb = bx - 1;             // 0..2047
    int e  = wb >> 7;
    int nt = (wb >> 4) & 7;
    int kg = wb & 15;            // 64-k group
    int n    = t & 127;          // lane-contiguous output column
    int half = t >> 7;

    const float* wp = w  + (size_t)e * (IN_F * OUT_F) + (size_t)nt * 128 + n;
    u16*         ob = wT + ((size_t)(e * 8 + nt)) * 131072 + (size_t)n * 8;

#pragma unroll
    for (int i = 0; i < 4; ++i) {
        int kog = kg * 8 + half + i * 2;   // global k-octet
        float r[8];
#pragma unroll
        for (int j = 0; j < 8; ++j)
            r[j] = wp[(size_t)(kog * 8 + j) * OUT_F];   // 256 B/wave contiguous per instr
        union { __hip_bfloat162 h; uint32_t u; } c0, c1, c2, c3;
        c0.h = __float22bfloat162_rn(make_float2(r[0], r[1]));
        c1.h = __float22bfloat162_rn(make_float2(r[2], r[3]));
        c2.h = __float22bfloat162_rn(make_float2(r[4], r[5]));
        c3.h = __float22bfloat162_rn(make_float2(r[6], r[7]));
        union { s16x8 v; uint32_t u[4]; } outv;
        outv.u[0] = c0.u; outv.u[1] = c1.u; outv.u[2] = c2.u; outv.u[3] = c3.u;
        *(s16x8*)(ob + (size_t)kog * 1024) = outv.v;    // 1 KB/wave contiguous
    }
}

// ---------------- kernel 2: x-gather fp32 -> bf16 frag-major, NO LDS ----------------
// xg layout (u16): mt*131072 + kb*4096 + q*1024 + r*8 + j   (k = kb*32 + q*8 + j)
// per-wave: float4 gather forms 128 B segments per token row; us4 stores form
// 4 x 128 B contiguous segments per wave -> cache-line granular both ways.
#define XBLOCKS (MAX_MT * 8)    // (mt, 128-k group)

__global__ __launch_bounds__(256)
void xprep_kernel(const float* __restrict__ x,
                  const int* __restrict__ perm, const int* __restrict__ offs,
                  const int* __restrict__ tile_off,
                  u16* __restrict__ xg)
{
    int t  = threadIdx.x;
    int bx = blockIdx.x;
    int mt = bx >> 3;
    int kg = bx & 7;             // 128-k group
    int total = tile_off[N_MODELS];
    if (mt >= total) return;
    int e = 0;
    while (tile_off[e + 1] <= mt) ++e;
    int s0   = offs[e] + (mt - tile_off[e]) * 128;
    int sEnd = offs[e + 1];

    int r0   = t >> 3;           // 0..31
    int apos = t & 7;
    int q    = apos >> 1;
    int j0   = (apos & 1) * 4;

    int toks[4];
#pragma unroll
    for (int i = 0; i < 4; ++i) {
        int r = r0 + i * 32;
        toks[i] = (s0 + r < sEnd) ? perm[s0 + r] : -1;
    }

    u16* outx = xg + (size_t)mt * 131072;
#pragma unroll
    for (int kb4 = 0; kb4 < 4; ++kb4) {
        int kb = kg * 4 + kb4;
        int k  = kb * 32 + apos * 4;
#pragma unroll
        for (int i = 0; i < 4; ++i) {
            int r = r0 + i * 32;
            float4 v;
            if (toks[i] >= 0) v = *(const float4*)(x + (size_t)toks[i] * IN_F + k);
            else              v = make_float4(0.f, 0.f, 0.f, 0.f);
            us4 pk; pk.x = f2bf(v.x); pk.y = f2bf(v.y); pk.z = f2bf(v.z); pk.w = f2bf(v.w);
            *(us4*)(outx + (size_t)kb * 4096 + (size_t)q * 1024 + r * 8 + j0) = pk;
        }
    }
}

// ---------------- kernel 3: grouped GEMM + bias + relu ----------------
// Changes this round:
//  (a) T1 XCD-chunked bijective swizzle: 640 blocks = 8 XCDs x 80; each XCD gets
//      10 consecutive bt x all 8 nt -> atile (256 KB) and active wT tiles stay in
//      that XCD's 4 MB L2 instead of being re-fetched from HBM 8x / 4x.
//  (b) BK=64: two 4 KB k-slabs per LDS buffer (32 KB LDS), halves barrier count
//      (32 -> 16 K-iterations) with identical 2-phase sync semantics.
__global__ __launch_bounds__(256)
void gemm_kernel(const u16* __restrict__ xg, const u16* __restrict__ wT,
                 const float* __restrict__ bias,
                 const int* __restrict__ perm, const int* __restrict__ offs,
                 const int* __restrict__ tile_off,
                 float* __restrict__ out)
{
    __shared__ u16 As[8192];    // 16 KB: two 4096-u16 k-slabs
    __shared__ u16 Bs[8192];
    __shared__ int   permS[128];
    __shared__ float biasS[128];
    __shared__ int   toS[N_MODELS + 1];

    int t = threadIdx.x;
    // XCD-chunked bijective swizzle: o%8 = hardware XCD; give each XCD a
    // contiguous wgid chunk of 80 (= MAX_MT), bt-major within the chunk.
    int o    = blockIdx.x;               // 0..639
    int wgid = (o & 7) * MAX_MT + (o >> 3);
    int bt   = wgid >> 3;                // m-tile id
    int nt   = wgid & 7;                 // n-tile id

    if (t <= N_MODELS) toS[t] = tile_off[t];
    __syncthreads();
    if (bt >= toS[N_MODELS]) return;   // uniform

    int e = 0;
    while (toS[e + 1] <= bt) ++e;
    int s0   = offs[e] + (bt - toS[e]) * 128;
    int sEnd = offs[e + 1];
    int mValid = sEnd - s0; if (mValid > 128) mValid = 128;

    if (t < 128) {
        permS[t] = (s0 + t < sEnd) ? perm[s0 + t] : 0;
        biasS[t] = bias[(size_t)e * OUT_F + nt * 128 + t];
    }

    const u16* atile = xg + (size_t)bt * 32 * 4096;
    const u16* btile = wT + ((size_t)(e * 8 + nt)) * 131072;

    int lane = t & 63;
    int wv   = t >> 6;
    int wm   = (wv >> 1) * 64;
    int wn   = (wv & 1) * 64;
    int m    = lane & 15;
    int q    = lane >> 4;

    f32x4 acc[4][4];
#pragma unroll
    for (int i = 0; i < 4; ++i)
#pragma unroll
        for (int j = 0; j < 4; ++j)
            acc[i][j] = (f32x4){0.f, 0.f, 0.f, 0.f};

    int c = wv * 2;   // this wave's 1 KB chunk base (8 chunks per 8 KB slab)

    for (int kb2 = 0; kb2 < 16; ++kb2) {
        const u16* ga = atile + kb2 * 8192;
        const u16* gb = btile + kb2 * 8192;
        // stage 32 KB (two slabs each of A and B); 8 DMA ops per wave
        gload16(ga + (c    ) * 512 + lane * 8, &As[(c    ) * 512]);
        gload16(ga + (c + 1) * 512 + lane * 8, &As[(c + 1) * 512]);
        gload16(ga + 4096 + (c    ) * 512 + lane * 8, &As[4096 + (c    ) * 512]);
        gload16(ga + 4096 + (c + 1) * 512 + lane * 8, &As[4096 + (c + 1) * 512]);
        gload16(gb + (c    ) * 512 + lane * 8, &Bs[(c    ) * 512]);
        gload16(gb + (c + 1) * 512 + lane * 8, &Bs[(c + 1) * 512]);
        gload16(gb + 4096 + (c    ) * 512 + lane * 8, &Bs[4096 + (c    ) * 512]);
        gload16(gb + 4096 + (c + 1) * 512 + lane * 8, &Bs[4096 + (c + 1) * 512]);
        __syncthreads();

#pragma unroll
        for (int s = 0; s < 2; ++s) {
            s16x8 af[4], bf[4];
#pragma unroll
            for (int mt2 = 0; mt2 < 4; ++mt2)
                af[mt2] = *(const s16x8*)(&As[s * 4096 + q * 1024 + (wm + mt2 * 16 + m) * 8]);
#pragma unroll
            for (int nt2 = 0; nt2 < 4; ++nt2)
                bf[nt2] = *(const s16x8*)(&Bs[s * 4096 + q * 1024 + (wn + nt2 * 16 + m) * 8]);
#pragma unroll
            for (int mt2 = 0; mt2 < 4; ++mt2)
#pragma unroll
                for (int nt2 = 0; nt2 < 4; ++nt2)
                    acc[mt2][nt2] = __builtin_amdgcn_mfma_f32_16x16x32_bf16(
                        af[mt2], bf[nt2], acc[mt2][nt2], 0, 0, 0);
        }
        __syncthreads();
    }

    // epilogue: bias + relu, scatter rows by perm
#pragma unroll
    for (int mt2 = 0; mt2 < 4; ++mt2) {
        int rbase = wm + mt2 * 16 + q * 4;
#pragma unroll
        for (int i = 0; i < 4; ++i) {
            int r = rbase + i;
            if (r < mValid) {
                int tok = permS[r];
                float* orow = out + (size_t)tok * OUT_F + nt * 128;
#pragma unroll
                for (int nt2 = 0; nt2 < 4; ++nt2) {
                    int col = wn + nt2 * 16 + m;
                    float v = acc[mt2][nt2][i] + biasS[col];
                    orow[col] = v > 0.f ? v : 0.f;
                }
            }
        }
    }
}

extern "C" void kernel_launch(void* const* d_in, const int* in_sizes, int n_in,
                              void* d_out, int out_size, void* d_ws, size_t ws_size,
                              hipStream_t stream) {
    const float* x    = (const float*)d_in[0];
    const int*   idxs = (const int*)d_in[1];
    const float* w    = (const float*)d_in[2];
    const float* b    = (const float*)d_in[3];
    float* out = (float*)d_out;

    // ws layout: wT u16[16M] (32 MB) | xg u16[80*32*4096] (20 MB) | perm | offs | tile_off
    u16* wT = (u16*)d_ws;
    u16* xg = wT + (size_t)N_MODELS * IN_F * OUT_F;
    int* perm     = (int*)(xg + (size_t)MAX_MT * 32 * 4096);
    int* offs     = perm + N_TOK;
    int* tile_off = offs + (N_MODELS + 1);

    // block 0 = setup (independent of w-blocks; x-gather launches after, so the
    // dependency is satisfied by kernel-boundary ordering regardless of dispatch order)
    wprep_setup_kernel<<<WBLOCKS + 1, 256, 0, stream>>>(w, idxs, perm, offs, tile_off, wT);
    xprep_kernel<<<XBLOCKS, 256, 0, stream>>>(x, perm, offs, tile_off, xg);
    gemm_kernel<<<8 * MAX_MT, 256, 0, stream>>>(xg, wT, b, perm, offs, tile_off, out);
}

// Round 3
// 180.034 us; speedup vs baseline: 1.0239x; 1.0033x over previous
//
#include <hip/hip_runtime.h>
#include <hip/hip_bf16.h>
#include <stdint.h>

#define N_MODELS 16
#define IN_F 1024
#define OUT_F 1024
#define N_TOK 8192
#define MAX_MT 80          // max m-tiles: 64 full + up to 15 fragmentation

typedef unsigned short u16;
using us4   = __attribute__((ext_vector_type(4))) unsigned short;
using s16x8 = __attribute__((ext_vector_type(8))) short;
using f32x4 = __attribute__((ext_vector_type(4))) float;

__device__ __forceinline__ u16 f2bf(float f) {
    union { float f; uint32_t u; } v;
    v.f = f;
    uint32_t u = v.u;
    u += 0x7fffu + ((u >> 16) & 1u);   // RNE
    return (u16)(u >> 16);
}

__device__ __forceinline__ void gload16(const u16* g, u16* l) {
    // async global->LDS DMA, 16 B/lane; LDS dest = wave-uniform base + lane*16
    __builtin_amdgcn_global_load_lds(
        (const __attribute__((address_space(1))) void*)g,
        (__attribute__((address_space(3))) void*)l, 16, 0, 0);
}

// ---------------- kernel 1: fused w-convert (blocks 1..2048) + setup (block 0) ----------------
// wT layout (u16): (e*8 + nt)*131072 + ko_g*1024 + n*8 + j    (ko_g: global k-octet 0..127)
#define ROW 17   // LDS row stride (ints) for [256][16] tables -> conflict-free
#define WBLOCKS 2048   // (e, nt, 64-k group)

__global__ __launch_bounds__(256)
void wprep_setup_kernel(const float* __restrict__ w,
                        const int* __restrict__ idxs,
                        int* __restrict__ perm,
                        int* __restrict__ offs,       // [17]
                        int* __restrict__ tile_off,   // [17]
                        u16* __restrict__ wT)
{
    __shared__ int cnt[256 * ROW];
    __shared__ int offsS[N_MODELS + 1];
    int t  = threadIdx.x;
    int bx = blockIdx.x;

    if (bx == 0) {
        // ---- setup: histogram + scan + rank scatter ----
#pragma unroll
        for (int e = 0; e < N_MODELS; ++e) cnt[t * ROW + e] = 0;
        __syncthreads();

        int base = t * 32;
#pragma unroll
        for (int i = 0; i < 32; ++i) cnt[t * ROW + idxs[base + i]] += 1;
        __syncthreads();

#pragma unroll
        for (int s = 1; s < 256; s <<= 1) {
            int v[N_MODELS];
#pragma unroll
            for (int e = 0; e < N_MODELS; ++e)
                v[e] = (t >= s) ? cnt[(t - s) * ROW + e] : 0;
            __syncthreads();
#pragma unroll
            for (int e = 0; e < N_MODELS; ++e)
                cnt[t * ROW + e] += v[e];
            __syncthreads();
        }

        if (t == 0) {
            int o = 0, to = 0;
            for (int e = 0; e < N_MODELS; ++e) {
                int c = cnt[255 * ROW + e];
                offsS[e] = o;
                offs[e] = o; tile_off[e] = to;
                to += (c + 127) >> 7;
                o  += c;
            }
            offsS[N_MODELS] = o;
            offs[N_MODELS] = o; tile_off[N_MODELS] = to;
        }
        __syncthreads();

        int cur[N_MODELS];
#pragma unroll
        for (int e = 0; e < N_MODELS; ++e)
            cur[e] = offsS[e] + ((t > 0) ? cnt[(t - 1) * ROW + e] : 0);
        __syncthreads();
#pragma unroll
        for (int e = 0; e < N_MODELS; ++e) cnt[t * ROW + e] = cur[e];

#pragma unroll
        for (int i = 0; i < 32; ++i) {
            int tok = base + i;
            int e = idxs[tok];
            perm[cnt[t * ROW + e]++] = tok;
        }
        return;
    }

    // ---- w-path: direct strided-coalesced transform, no LDS / no barriers ----
    int wb = bx - 1;             // 0..2047
    int e  = wb >> 7;
    int nt = (wb >> 4) & 7;
    int kg = wb & 15;            // 64-k group
    int n    = t & 127;          // lane-contiguous output column
    int half = t >> 7;

    const float* wp = w  + (size_t)e * (IN_F * OUT_F) + (size_t)nt * 128 + n;
    u16*         ob = wT + ((size_t)(e * 8 + nt)) * 131072 + (size_t)n * 8;

#pragma unroll
    for (int i = 0; i < 4; ++i) {
        int kog = kg * 8 + half + i * 2;   // global k-octet
        float r[8];
#pragma unroll
        for (int j = 0; j < 8; ++j)
            r[j] = wp[(size_t)(kog * 8 + j) * OUT_F];   // 256 B/wave contiguous per instr
        union { __hip_bfloat162 h; uint32_t u; } c0, c1, c2, c3;
        c0.h = __float22bfloat162_rn(make_float2(r[0], r[1]));
        c1.h = __float22bfloat162_rn(make_float2(r[2], r[3]));
        c2.h = __float22bfloat162_rn(make_float2(r[4], r[5]));
        c3.h = __float22bfloat162_rn(make_float2(r[6], r[7]));
        union { s16x8 v; uint32_t u[4]; } outv;
        outv.u[0] = c0.u; outv.u[1] = c1.u; outv.u[2] = c2.u; outv.u[3] = c3.u;
        *(s16x8*)(ob + (size_t)kog * 1024) = outv.v;    // 1 KB/wave contiguous
    }
}

// ---------------- kernel 2: x-gather fp32 -> bf16 frag-major, NO LDS ----------------
// xg layout (u16): mt*131072 + kb*4096 + q*1024 + r*8 + j   (k = kb*32 + q*8 + j)
#define XBLOCKS (MAX_MT * 8)    // (mt, 128-k group)

__global__ __launch_bounds__(256)
void xprep_kernel(const float* __restrict__ x,
                  const int* __restrict__ perm, const int* __restrict__ offs,
                  const int* __restrict__ tile_off,
                  u16* __restrict__ xg)
{
    int t  = threadIdx.x;
    int bx = blockIdx.x;
    int mt = bx >> 3;
    int kg = bx & 7;             // 128-k group
    int total = tile_off[N_MODELS];
    if (mt >= total) return;
    int e = 0;
    while (tile_off[e + 1] <= mt) ++e;
    int s0   = offs[e] + (mt - tile_off[e]) * 128;
    int sEnd = offs[e + 1];

    int r0   = t >> 3;           // 0..31
    int apos = t & 7;
    int q    = apos >> 1;
    int j0   = (apos & 1) * 4;

    int toks[4];
#pragma unroll
    for (int i = 0; i < 4; ++i) {
        int r = r0 + i * 32;
        toks[i] = (s0 + r < sEnd) ? perm[s0 + r] : -1;
    }

    u16* outx = xg + (size_t)mt * 131072;
#pragma unroll
    for (int kb4 = 0; kb4 < 4; ++kb4) {
        int kb = kg * 4 + kb4;
        int k  = kb * 32 + apos * 4;
#pragma unroll
        for (int i = 0; i < 4; ++i) {
            int r = r0 + i * 32;
            float4 v;
            if (toks[i] >= 0) v = *(const float4*)(x + (size_t)toks[i] * IN_F + k);
            else              v = make_float4(0.f, 0.f, 0.f, 0.f);
            us4 pk; pk.x = f2bf(v.x); pk.y = f2bf(v.y); pk.z = f2bf(v.z); pk.w = f2bf(v.w);
            *(us4*)(outx + (size_t)kb * 4096 + (size_t)q * 1024 + r * 8 + j0) = pk;
        }
    }
}

// ---------------- kernel 3: grouped GEMM + bias + relu ----------------
// This round:
//  (a) A-operand direct global->VGPR (xg is frag-major; L2-resident via XCD swizzle).
//      A never touches LDS -> LDS read traffic halved, no barrier dependency for A;
//      a0/a1 register rotation prefetches a full compute phase ahead.
//  (b) B double-buffered in LDS, staged immediately AFTER the barrier so the
//      auto vmcnt(0) drain at the NEXT barrier waits on loads issued a full
//      compute phase earlier (T3-minimum 2-phase). 1 barrier per 64-k step.
//  (c) __launch_bounds__(256,3): cap VGPR so 3 blocks/CU stay resident.
__global__ __launch_bounds__(256, 3)
void gemm_kernel(const u16* __restrict__ xg, const u16* __restrict__ wT,
                 const float* __restrict__ bias,
                 const int* __restrict__ perm, const int* __restrict__ offs,
                 const int* __restrict__ tile_off,
                 float* __restrict__ out)
{
    __shared__ u16 Bs[2][8192];      // 32 KB: double-buffered 64-k B tile
    __shared__ int   permS[128];
    __shared__ float biasS[128];
    __shared__ int   toS[N_MODELS + 1];

    int t = threadIdx.x;
    // XCD-chunked bijective swizzle (640 = 8 x 80): each XCD gets 10 consecutive
    // bt x all 8 nt -> xg tiles and wT panels stay in that XCD's L2.
    int o    = blockIdx.x;               // 0..639
    int wgid = (o & 7) * MAX_MT + (o >> 3);
    int bt   = wgid >> 3;                // m-tile id
    int nt   = wgid & 7;                 // n-tile id

    if (t <= N_MODELS) toS[t] = tile_off[t];
    __syncthreads();
    if (bt >= toS[N_MODELS]) return;   // uniform

    int e = 0;
    while (toS[e + 1] <= bt) ++e;
    int s0   = offs[e] + (bt - toS[e]) * 128;
    int sEnd = offs[e + 1];
    int mValid = sEnd - s0; if (mValid > 128) mValid = 128;

    if (t < 128) {
        permS[t] = (s0 + t < sEnd) ? perm[s0 + t] : 0;
        biasS[t] = bias[(size_t)e * OUT_F + nt * 128 + t];
    }
    // published by the loop's first __syncthreads()

    const u16* atile = xg + (size_t)bt * 131072;
    const u16* btile = wT + ((size_t)(e * 8 + nt)) * 131072;

    int lane = t & 63;
    int wv   = t >> 6;
    int wm   = (wv >> 1) * 64;
    int wn   = (wv & 1) * 64;
    int m    = lane & 15;
    int q    = lane >> 4;

    int aoff = q * 1024 + (wm + m) * 8;   // u16 offset of this lane's A frag in a 32-k slab
    int boff = q * 1024 + (wn + m) * 8;   // same for B within staged LDS slab

    f32x4 acc[4][4];
#pragma unroll
    for (int i = 0; i < 4; ++i)
#pragma unroll
        for (int j = 0; j < 4; ++j)
            acc[i][j] = (f32x4){0.f, 0.f, 0.f, 0.f};

    // prologue: stage B(kb2=0), load A slab0+slab1 of kb2=0 into registers
#pragma unroll
    for (int i = 0; i < 4; ++i)
        gload16(btile + wv * 2048 + i * 512 + lane * 8, &Bs[0][wv * 2048 + i * 512]);

    s16x8 a0[4], a1[4];
#pragma unroll
    for (int mt2 = 0; mt2 < 4; ++mt2)
        a0[mt2] = *(const s16x8*)(atile + aoff + mt2 * 128);
#pragma unroll
    for (int mt2 = 0; mt2 < 4; ++mt2)
        a1[mt2] = *(const s16x8*)(atile + 4096 + aoff + mt2 * 128);

    for (int kb2 = 0; kb2 < 16; ++kb2) {
        int cur = kb2 & 1;
        __syncthreads();   // auto vmcnt(0) drain: B(kb2) + in-flight A-loads complete
        if (kb2 < 15) {
            const u16* gb = btile + (size_t)(kb2 + 1) * 8192;
#pragma unroll
            for (int i = 0; i < 4; ++i)
                gload16(gb + wv * 2048 + i * 512 + lane * 8,
                        &Bs[cur ^ 1][wv * 2048 + i * 512]);
        }
        if (kb2 > 0) {   // A slab1 of THIS kb2; covered by slab0 compute below
#pragma unroll
            for (int mt2 = 0; mt2 < 4; ++mt2)
                a1[mt2] = *(const s16x8*)(atile + (size_t)kb2 * 8192 + 4096 + aoff + mt2 * 128);
        }

        // ---- slab 0 ----
        s16x8 bf[4];
#pragma unroll
        for (int nt2 = 0; nt2 < 4; ++nt2)
            bf[nt2] = *(const s16x8*)(&Bs[cur][boff + nt2 * 128]);
#pragma unroll
        for (int mt2 = 0; mt2 < 4; ++mt2)
#pragma unroll
            for (int nt2 = 0; nt2 < 4; ++nt2)
                acc[mt2][nt2] = __builtin_amdgcn_mfma_f32_16x16x32_bf16(
                    a0[mt2], bf[nt2], acc[mt2][nt2], 0, 0, 0);

        if (kb2 < 15) {   // A slab0 of NEXT kb2; flies during slab1 compute + drain
#pragma unroll
            for (int mt2 = 0; mt2 < 4; ++mt2)
                a0[mt2] = *(const s16x8*)(atile + (size_t)(kb2 + 1) * 8192 + aoff + mt2 * 128);
        }

        // ---- slab 1 ----
#pragma unroll
        for (int nt2 = 0; nt2 < 4; ++nt2)
            bf[nt2] = *(const s16x8*)(&Bs[cur][4096 + boff + nt2 * 128]);
#pragma unroll
        for (int mt2 = 0; mt2 < 4; ++mt2)
#pragma unroll
            for (int nt2 = 0; nt2 < 4; ++nt2)
                acc[mt2][nt2] = __builtin_amdgcn_mfma_f32_16x16x32_bf16(
                    a1[mt2], bf[nt2], acc[mt2][nt2], 0, 0, 0);
    }

    // epilogue: bias + relu, scatter rows by perm
#pragma unroll
    for (int mt2 = 0; mt2 < 4; ++mt2) {
        int rbase = wm + mt2 * 16 + q * 4;
#pragma unroll
        for (int i = 0; i < 4; ++i) {
            int r = rbase + i;
            if (r < mValid) {
                int tok = permS[r];
                float* orow = out + (size_t)tok * OUT_F + nt * 128;
#pragma unroll
                for (int nt2 = 0; nt2 < 4; ++nt2) {
                    int col = wn + nt2 * 16 + m;
                    float v = acc[mt2][nt2][i] + biasS[col];
                    orow[col] = v > 0.f ? v : 0.f;
                }
            }
        }
    }
}

extern "C" void kernel_launch(void* const* d_in, const int* in_sizes, int n_in,
                              void* d_out, int out_size, void* d_ws, size_t ws_size,
                              hipStream_t stream) {
    const float* x    = (const float*)d_in[0];
    const int*   idxs = (const int*)d_in[1];
    const float* w    = (const float*)d_in[2];
    const float* b    = (const float*)d_in[3];
    float* out = (float*)d_out;

    // ws layout: wT u16[16M] (32 MB) | xg u16[80*32*4096] (20 MB) | perm | offs | tile_off
    u16* wT = (u16*)d_ws;
    u16* xg = wT + (size_t)N_MODELS * IN_F * OUT_F;
    int* perm     = (int*)(xg + (size_t)MAX_MT * 32 * 4096);
    int* offs     = perm + N_TOK;
    int* tile_off = offs + (N_MODELS + 1);

    wprep_setup_kernel<<<WBLOCKS + 1, 256, 0, stream>>>(w, idxs, perm, offs, tile_off, wT);
    xprep_kernel<<<XBLOCKS, 256, 0, stream>>>(x, perm, offs, tile_off, xg);
    gemm_kernel<<<8 * MAX_MT, 256, 0, stream>>>(xg, wT, b, perm, offs, tile_off, out);
}